// Round 13
// baseline (1198.715 us; speedup 1.0000x reference)
//
#include <hip/hip_runtime.h>

#define NPTS 8192
#define NSAMP 1024
#define NBATCH 8
#define KNB 32

typedef float f32x2 __attribute__((ext_vector_type(2)));
typedef unsigned long long u64;

// Packed f32 ops — IEEE rn per half, identical results to scalar v_add/v_mul.
__device__ __forceinline__ f32x2 pk_add(f32x2 a, f32x2 b) {
  f32x2 d; asm("v_pk_add_f32 %0, %1, %2" : "=v"(d) : "v"(a), "v"(b)); return d;
}
__device__ __forceinline__ f32x2 pk_mul(f32x2 a, f32x2 b) {
  f32x2 d; asm("v_pk_mul_f32 %0, %1, %2" : "=v"(d) : "v"(a), "v"(b)); return d;
}

// Single-dep-chain DPP reduce rounds (old = own value, safe for min/max).
#define DPP_FMAX_ROUND(v, CTRL)                                                        \
  do {                                                                                 \
    int _b = __float_as_int(v);                                                        \
    int _p = __builtin_amdgcn_update_dpp(_b, _b, CTRL, 0xF, 0xF, false);               \
    (v) = fmaxf((v), __int_as_float(_p));                                              \
  } while (0)

#define DPP_FMIN_ROUND(v, CTRL)                                                        \
  do {                                                                                 \
    int _b = __float_as_int(v);                                                        \
    int _p = __builtin_amdgcn_update_dpp(_b, _b, CTRL, 0xF, 0xF, false);               \
    (v) = fminf((v), __int_as_float(_p));                                              \
  } while (0)

#define DPP_UMIN_ROUND(v, CTRL)                                                        \
  do {                                                                                 \
    unsigned _p = (unsigned)__builtin_amdgcn_update_dpp((int)(v), (int)(v), CTRL,      \
                                                        0xF, 0xF, false);              \
    if (_p < (v)) (v) = _p;                                                            \
  } while (0)

// u64 key min round — used for the 3 cross-wave rounds.
#define DPP_MIN_ROUND(k, CTRL)                                                         \
  do {                                                                                 \
    unsigned _lo = (unsigned)(k), _hi = (unsigned)((k) >> 32);                         \
    unsigned _plo = (unsigned)__builtin_amdgcn_update_dpp((int)_lo, (int)_lo, CTRL,    \
                                                          0xF, 0xF, false);            \
    unsigned _phi = (unsigned)__builtin_amdgcn_update_dpp((int)_hi, (int)_hi, CTRL,    \
                                                          0xF, 0xF, false);            \
    u64 _ok = (((u64)_phi) << 32) | _plo;                                              \
    if (_ok < (k)) (k) = _ok;                                                          \
  } while (0)

// Exact-match squared distance: ((dx*dx + dy*dy) + dz*dz), rn ops, no FMA.
__device__ __forceinline__ float sqdist_rn(float px, float py, float pz,
                                           float qx, float qy, float qz) {
  float dx = px - qx, dy = py - qy, dz = pz - qz;
  return __fadd_rn(__fadd_rn(__fmul_rn(dx, dx), __fmul_rn(dy, dy)), __fmul_rn(dz, dz));
}

// ---------------------------------------------------------------------------
// Kernel 1: farthest point sampling (R7 structure — measured 953 us, stable
// across 3 runs; 7 structural variants all measured worse).
// ---------------------------------------------------------------------------
__global__ __launch_bounds__(512) void fps_kernel(const float* __restrict__ xyz,
                                                  float* __restrict__ out_newxyz) {
  __shared__ __align__(16) char smem_raw[NPTS * 3 * 4];
  u64* sbuf = reinterpret_cast<u64*>(smem_raw);
  float* cds = reinterpret_cast<float*>(smem_raw);  // [n]={x,y,z}, stride 12B
  __shared__ u64 wkeys[2][8];

  const int b = blockIdx.x;
  const int tid = threadIdx.x;
  const int lane = tid & 63;
  const int wv = tid >> 6;
  const float* xb = xyz + (size_t)b * 3 * NPTS;

  // phase 0: sort keys (x >= 0 so u32 bit order == float order)
  for (int j = 0; j < 16; j++) {
    int n = tid + j * 512;
    float x = xb[n];
    sbuf[n] = (((u64)__float_as_uint(x)) << 32) | (u64)n;
  }
  __syncthreads();

  // bitonic sort ascending, 8192 u64 keys in LDS
  for (unsigned k = 2; k <= (unsigned)NPTS; k <<= 1) {
    for (unsigned jm = k >> 1; jm > 0; jm >>= 1) {
      for (int p = 0; p < 16; p++) {
        unsigned i = (unsigned)tid + (unsigned)p * 512u;
        unsigned ixj = i ^ jm;
        if (ixj > i) {
          u64 a = sbuf[i], c = sbuf[ixj];
          bool up = ((i & k) == 0);
          if ((a > c) == up) { sbuf[i] = c; sbuf[ixj] = a; }
        }
      }
      __syncthreads();
    }
  }

  // phase 1: thread t takes sorted slots [t*16, t*16+16)
  f32x2 X2[8], Y2[8], Z2[8], D2[8];
  unsigned idxp[8];
  float txmin = 1e30f, txmax = -1e30f;
#pragma unroll
  for (int j = 0; j < 8; j++) {
    u64 k0 = sbuf[tid * 16 + 2 * j];
    u64 k1 = sbuf[tid * 16 + 2 * j + 1];
    unsigned n0 = (unsigned)k0 & 8191u, n1 = (unsigned)k1 & 8191u;
    float x0 = __uint_as_float((unsigned)(k0 >> 32));
    float x1 = __uint_as_float((unsigned)(k1 >> 32));
    X2[j].x = x0; X2[j].y = x1;
    Y2[j].x = xb[NPTS + n0];     Y2[j].y = xb[NPTS + n1];
    Z2[j].x = xb[2 * NPTS + n0]; Z2[j].y = xb[2 * NPTS + n1];
    D2[j].x = 1e10f;             D2[j].y = 1e10f;
    idxp[j] = n0 | (n1 << 16);
    txmin = fminf(txmin, fminf(x0, x1));
    txmax = fmaxf(txmax, fmaxf(x0, x1));
  }
  DPP_FMIN_ROUND(txmin, 0x111); DPP_FMIN_ROUND(txmin, 0x112);
  DPP_FMIN_ROUND(txmin, 0x114); DPP_FMIN_ROUND(txmin, 0x118);
  DPP_FMIN_ROUND(txmin, 0x142); DPP_FMIN_ROUND(txmin, 0x143);
  DPP_FMAX_ROUND(txmax, 0x111); DPP_FMAX_ROUND(txmax, 0x112);
  DPP_FMAX_ROUND(txmax, 0x114); DPP_FMAX_ROUND(txmax, 0x118);
  DPP_FMAX_ROUND(txmax, 0x142); DPP_FMAX_ROUND(txmax, 0x143);
  const float xlo = __int_as_float(__builtin_amdgcn_readlane(__float_as_int(txmin), 63));
  const float xhi = __int_as_float(__builtin_amdgcn_readlane(__float_as_int(txmax), 63));
  __syncthreads();

  // phase 2: overlay cds (coords by ORIGINAL index)
#pragma unroll
  for (int j = 0; j < 8; j++) {
    unsigned n0 = idxp[j] & 0xFFFFu, n1 = idxp[j] >> 16;
    cds[n0 * 3 + 0] = X2[j].x; cds[n0 * 3 + 1] = Y2[j].x; cds[n0 * 3 + 2] = Z2[j].x;
    cds[n1 * 3 + 0] = X2[j].y; cds[n1 * 3 + 1] = Y2[j].y; cds[n1 * 3 + 2] = Z2[j].y;
  }
  __syncthreads();

  float sx = cds[0], sy = cds[1], sz = cds[2];
  unsigned c0i = 0, c1i = 0;
  float bv_cache = 1e10f;
  u64 key_cache = ~0ull;

  for (int t = 0; t < NSAMP; t++) {
    float gap = fmaxf(fmaxf(xlo - sx, sx - xhi), 0.0f);
    float lb = __fmul_rn(gap, gap);

    if (lb < bv_cache) {
      f32x2 nqx, nqy, nqz;
      nqx.x = -sx; nqx.y = -sx;
      nqy.x = -sy; nqy.y = -sy;
      nqz.x = -sz; nqz.y = -sz;
      float bvx = -1.0f, bvy = -1.0f;
#pragma unroll
      for (int j = 0; j < 8; j++) {
        f32x2 dx = pk_add(X2[j], nqx);
        f32x2 dy = pk_add(Y2[j], nqy);
        f32x2 dz = pk_add(Z2[j], nqz);
        f32x2 dd = pk_add(pk_add(pk_mul(dx, dx), pk_mul(dy, dy)), pk_mul(dz, dz));
        float m0 = fminf(D2[j].x, dd.x);
        float m1 = fminf(D2[j].y, dd.y);
        D2[j].x = m0;
        D2[j].y = m1;
        bvx = fmaxf(bvx, m0);
        bvy = fmaxf(bvy, m1);
      }
      float bv = fmaxf(bvx, bvy);

      DPP_FMAX_ROUND(bv, 0x111);
      DPP_FMAX_ROUND(bv, 0x112);
      DPP_FMAX_ROUND(bv, 0x114);
      DPP_FMAX_ROUND(bv, 0x118);
      DPP_FMAX_ROUND(bv, 0x142);
      DPP_FMAX_ROUND(bv, 0x143);
      float wval = __int_as_float(__builtin_amdgcn_readlane(__float_as_int(bv), 63));

      unsigned cand = 0xFFFFFFFFu;
#pragma unroll
      for (int j = 0; j < 8; j++) {
        unsigned n0 = idxp[j] & 0xFFFFu, n1 = idxp[j] >> 16;
        if (D2[j].y == wval && n1 < cand) cand = n1;
        if (D2[j].x == wval && n0 < cand) cand = n0;
      }
      DPP_UMIN_ROUND(cand, 0x111);
      DPP_UMIN_ROUND(cand, 0x112);
      DPP_UMIN_ROUND(cand, 0x114);
      DPP_UMIN_ROUND(cand, 0x118);
      DPP_UMIN_ROUND(cand, 0x142);
      DPP_UMIN_ROUND(cand, 0x143);

      key_cache = (((u64)(~__float_as_uint(wval))) << 32) | (u64)cand;
      bv_cache = wval;
    }

    const int par = t & 1;
    if (lane == 63) wkeys[par][wv] = key_cache;
    __syncthreads();
    u64 k8 = wkeys[par][lane & 7];
    DPP_MIN_ROUND(k8, 0xB1);   // quad_perm ^1
    DPP_MIN_ROUND(k8, 0x4E);   // quad_perm ^2
    DPP_MIN_ROUND(k8, 0x141);  // row_half_mirror
    unsigned wid = (unsigned)__builtin_amdgcn_readfirstlane((int)(unsigned)k8);

    if (t + 1 == tid) c0i = wid;
    if (t + 1 == tid + 512) c1i = wid;

    sx = cds[wid * 3 + 0];
    sy = cds[wid * 3 + 1];
    sz = cds[wid * 3 + 2];
  }

  {
    float ax = cds[c0i * 3 + 0], ay = cds[c0i * 3 + 1], az = cds[c0i * 3 + 2];
    float bx = cds[c1i * 3 + 0], by = cds[c1i * 3 + 1], bz = cds[c1i * 3 + 2];
    out_newxyz[(b * 3 + 0) * NSAMP + tid] = ax;
    out_newxyz[(b * 3 + 1) * NSAMP + tid] = ay;
    out_newxyz[(b * 3 + 2) * NSAMP + tid] = az;
    out_newxyz[(b * 3 + 0) * NSAMP + 512 + tid] = bx;
    out_newxyz[(b * 3 + 1) * NSAMP + 512 + tid] = by;
    out_newxyz[(b * 3 + 2) * NSAMP + 512 + tid] = bz;
  }
}

// ---------------------------------------------------------------------------
// Kernel 2 (fused consumer): per sample — ball query (wave 0, indices to
// LDS) + attention mean + gather + 3-layer MLP + max-pool. One 256-thread
// block per (b,s). LDS-pipe-optimized layout: each thread owns 4 output rows
// (weights via VMEM/L1-broadcast) so each LDS read feeds 2x the FMAs:
//   L0/L1: og=t>>4 (rows 4og..4og+3), kq=t&15 (k-pair, float2 reads)
//   L2:    og2=t>>3 (rows 4og2..4og2+3), kq2=t&7 (k-quad, one float4 read)
// Per-accumulator c-order remains ascending -> bitwise-identical output.
// ---------------------------------------------------------------------------
__global__ __launch_bounds__(256) void sample_kernel(
    const float* __restrict__ xyz, const float* __restrict__ pts,
    const float* __restrict__ att, const float* __restrict__ newxyz,
    const float* __restrict__ w0, const float* __restrict__ b0,
    const float* __restrict__ w1, const float* __restrict__ b1,
    const float* __restrict__ w2, const float* __restrict__ b2,
    float* __restrict__ out_np, float* __restrict__ att_out) {
  const int g = blockIdx.x;
  const int b = g >> 10;
  const int s = g & 1023;
  const int t = threadIdx.x;

  __shared__ __align__(16) float feat[67 * 32];
  __shared__ __align__(16) float h0s[64 * 36];
  __shared__ __align__(16) float h1s[64 * 36];
  __shared__ int sidx[KNB];
  __shared__ float qs[3];

  const float* xb = xyz + (size_t)b * 3 * NPTS;

  // ---- wave 0: ball query (first-K in index order) + attention mean ----
  if (t < 64) {
    const int lane = t;
    float qx = newxyz[(b * 3 + 0) * NSAMP + s];
    float qy = newxyz[(b * 3 + 1) * NSAMP + s];
    float qz = newxyz[(b * 3 + 2) * NSAMP + s];
    if (lane == 0) { qs[0] = qx; qs[1] = qy; qs[2] = qz; }

    int have = 0;
    int firstn = 0;
    for (int c = 0; c < NPTS / 64; c++) {
      int n = c * 64 + lane;
      float dd = sqdist_rn(xb[n], xb[NPTS + n], xb[2 * NPTS + n], qx, qy, qz);
      bool inb = (dd <= 0.04f);
      unsigned long long m = __ballot(inb);
      if (have == 0 && m != 0ull) firstn = c * 64 + __builtin_ctzll(m);
      int pre = __popcll(m & ((1ull << lane) - 1ull));
      if (inb && (have + pre) < KNB) sidx[have + pre] = n;
      have += __popcll(m);
      if (have >= KNB) break;
    }
    if (have > KNB) have = KNB;
    if (lane < KNB && lane >= have) sidx[lane] = firstn;  // pad with first hit

    float av = 0.0f;
    if (lane < KNB) av = att[(size_t)b * NPTS + sidx[lane]];
#pragma unroll
    for (int m = 1; m < 64; m <<= 1) av += __shfl_xor(av, m, 64);
    if (lane == 0) att_out[g] = av * 0.03125f;  // mean over K=32 (exact /32)
  }
  __syncthreads();

  // ---- gather: rows 0..2 = g_norm (xyz - query), rows 3..66 = features ----
  {
    int k = t & 31, rg = t >> 5;
    int n = sidx[k];
    const float* pb = pts + (size_t)b * 64 * NPTS;
    for (int r = rg; r < 67; r += 8) {
      float v;
      if (r < 3)
        v = xyz[((size_t)b * 3 + r) * NPTS + n] - qs[r];
      else
        v = pb[(size_t)(r - 3) * NPTS + n];
      feat[r * 32 + k] = v;
    }
  }
  __syncthreads();

  const int og = t >> 4;   // 0..15 -> rows 4og..4og+3
  const int kq = t & 15;   // k-pair {2kq, 2kq+1}

  // ---- layer 0: 67 -> 64 (4 rows x 2 k; scalar weight loads, stride 67) ----
  {
    float a[4][2];
#pragma unroll
    for (int r = 0; r < 4; r++) {
      float bb = b0[4 * og + r];
      a[r][0] = bb; a[r][1] = bb;
    }
    const float* wr0 = w0 + (4 * og + 0) * 67;
    const float* wr1 = w0 + (4 * og + 1) * 67;
    const float* wr2 = w0 + (4 * og + 2) * 67;
    const float* wr3 = w0 + (4 * og + 3) * 67;
    for (int c = 0; c < 67; c++) {
      float2 f = *(const float2*)&feat[c * 32 + 2 * kq];
      float u0 = wr0[c], u1 = wr1[c], u2 = wr2[c], u3 = wr3[c];
      a[0][0] = fmaf(u0, f.x, a[0][0]); a[0][1] = fmaf(u0, f.y, a[0][1]);
      a[1][0] = fmaf(u1, f.x, a[1][0]); a[1][1] = fmaf(u1, f.y, a[1][1]);
      a[2][0] = fmaf(u2, f.x, a[2][0]); a[2][1] = fmaf(u2, f.y, a[2][1]);
      a[3][0] = fmaf(u3, f.x, a[3][0]); a[3][1] = fmaf(u3, f.y, a[3][1]);
    }
#pragma unroll
    for (int r = 0; r < 4; r++) {
      float2 o;
      o.x = fmaxf(a[r][0], 0.f);
      o.y = fmaxf(a[r][1], 0.f);
      *(float2*)&h0s[(4 * og + r) * 36 + 2 * kq] = o;
    }
  }
  __syncthreads();

  // ---- layer 1: 64 -> 64 (4 rows x 2 k; float4 weight loads, stride 64) ----
  {
    float a[4][2];
#pragma unroll
    for (int r = 0; r < 4; r++) {
      float bb = b1[4 * og + r];
      a[r][0] = bb; a[r][1] = bb;
    }
    const float4* wv0 = (const float4*)(w1 + (4 * og + 0) * 64);
    const float4* wv1 = (const float4*)(w1 + (4 * og + 1) * 64);
    const float4* wv2 = (const float4*)(w1 + (4 * og + 2) * 64);
    const float4* wv3 = (const float4*)(w1 + (4 * og + 3) * 64);
    for (int c4 = 0; c4 < 16; c4++) {
      float4 q0 = wv0[c4], q1 = wv1[c4], q2 = wv2[c4], q3 = wv3[c4];
      float u0a[4] = {q0.x, q0.y, q0.z, q0.w};
      float u1a[4] = {q1.x, q1.y, q1.z, q1.w};
      float u2a[4] = {q2.x, q2.y, q2.z, q2.w};
      float u3a[4] = {q3.x, q3.y, q3.z, q3.w};
#pragma unroll
      for (int i = 0; i < 4; i++) {
        int c = c4 * 4 + i;
        float2 f = *(const float2*)&h0s[c * 36 + 2 * kq];
        a[0][0] = fmaf(u0a[i], f.x, a[0][0]); a[0][1] = fmaf(u0a[i], f.y, a[0][1]);
        a[1][0] = fmaf(u1a[i], f.x, a[1][0]); a[1][1] = fmaf(u1a[i], f.y, a[1][1]);
        a[2][0] = fmaf(u2a[i], f.x, a[2][0]); a[2][1] = fmaf(u2a[i], f.y, a[2][1]);
        a[3][0] = fmaf(u3a[i], f.x, a[3][0]); a[3][1] = fmaf(u3a[i], f.y, a[3][1]);
      }
    }
#pragma unroll
    for (int r = 0; r < 4; r++) {
      float2 o;
      o.x = fmaxf(a[r][0], 0.f);
      o.y = fmaxf(a[r][1], 0.f);
      *(float2*)&h1s[(4 * og + r) * 36 + 2 * kq] = o;
    }
  }
  __syncthreads();

  // ---- layer 2: 64 -> 128 (4 rows x 4 k; one float4 LDS read per c), pool ----
  {
    const int og2 = t >> 3;  // 0..31 -> rows 4og2..4og2+3
    const int kq2 = t & 7;   // k-quad 4kq2..4kq2+3
    float a[4][4];
#pragma unroll
    for (int r = 0; r < 4; r++) {
      float bb = b2[4 * og2 + r];
#pragma unroll
      for (int i = 0; i < 4; i++) a[r][i] = bb;
    }
    const float4* wv0 = (const float4*)(w2 + (4 * og2 + 0) * 64);
    const float4* wv1 = (const float4*)(w2 + (4 * og2 + 1) * 64);
    const float4* wv2 = (const float4*)(w2 + (4 * og2 + 2) * 64);
    const float4* wv3 = (const float4*)(w2 + (4 * og2 + 3) * 64);
    for (int c4 = 0; c4 < 16; c4++) {
      float4 q0 = wv0[c4], q1 = wv1[c4], q2 = wv2[c4], q3 = wv3[c4];
      float u0a[4] = {q0.x, q0.y, q0.z, q0.w};
      float u1a[4] = {q1.x, q1.y, q1.z, q1.w};
      float u2a[4] = {q2.x, q2.y, q2.z, q2.w};
      float u3a[4] = {q3.x, q3.y, q3.z, q3.w};
#pragma unroll
      for (int i = 0; i < 4; i++) {
        int c = c4 * 4 + i;
        float4 f = *(const float4*)&h1s[c * 36 + 4 * kq2];
        a[0][0] = fmaf(u0a[i], f.x, a[0][0]); a[0][1] = fmaf(u0a[i], f.y, a[0][1]);
        a[0][2] = fmaf(u0a[i], f.z, a[0][2]); a[0][3] = fmaf(u0a[i], f.w, a[0][3]);
        a[1][0] = fmaf(u1a[i], f.x, a[1][0]); a[1][1] = fmaf(u1a[i], f.y, a[1][1]);
        a[1][2] = fmaf(u1a[i], f.z, a[1][2]); a[1][3] = fmaf(u1a[i], f.w, a[1][3]);
        a[2][0] = fmaf(u2a[i], f.x, a[2][0]); a[2][1] = fmaf(u2a[i], f.y, a[2][1]);
        a[2][2] = fmaf(u2a[i], f.z, a[2][2]); a[2][3] = fmaf(u2a[i], f.w, a[2][3]);
        a[3][0] = fmaf(u3a[i], f.x, a[3][0]); a[3][1] = fmaf(u3a[i], f.y, a[3][1]);
        a[3][2] = fmaf(u3a[i], f.z, a[3][2]); a[3][3] = fmaf(u3a[i], f.w, a[3][3]);
      }
    }
    // relu then max over k == max then relu (relu is monotone)
#pragma unroll
    for (int r = 0; r < 4; r++) {
      float m = fmaxf(fmaxf(a[r][0], a[r][1]), fmaxf(a[r][2], a[r][3]));
      m = fmaxf(m, 0.f);
      // reduce across the 8 kq2 lanes sharing og2 (adjacent lanes)
      m = fmaxf(m, __shfl_xor(m, 1, 64));
      m = fmaxf(m, __shfl_xor(m, 2, 64));
      m = fmaxf(m, __shfl_xor(m, 4, 64));
      if (kq2 == 0)
        out_np[((size_t)b * 128 + 4 * og2 + r) * NSAMP + s] = m;
    }
  }
}

extern "C" void kernel_launch(void* const* d_in, const int* in_sizes, int n_in,
                              void* d_out, int out_size, void* d_ws, size_t ws_size,
                              hipStream_t stream) {
  (void)in_sizes; (void)n_in; (void)out_size; (void)d_ws; (void)ws_size;
  const float* xyz = (const float*)d_in[0];
  const float* pts = (const float*)d_in[1];
  const float* att = (const float*)d_in[2];
  const float* w0 = (const float*)d_in[3];
  const float* b0 = (const float*)d_in[4];
  const float* w1 = (const float*)d_in[5];
  const float* b1 = (const float*)d_in[6];
  const float* w2 = (const float*)d_in[7];
  const float* b2 = (const float*)d_in[8];

  float* out = (float*)d_out;
  float* out_newxyz = out;                                           // (B,3,S)
  float* out_newpts = out + NBATCH * 3 * NSAMP;                      // (B,128,S)
  float* out_att = out + NBATCH * 3 * NSAMP + NBATCH * 128 * NSAMP;  // (B,1,S)

  fps_kernel<<<NBATCH, 512, 0, stream>>>(xyz, out_newxyz);
  sample_kernel<<<NBATCH * NSAMP, 256, 0, stream>>>(
      xyz, pts, att, out_newxyz, w0, b0, w1, b1, w2, b2, out_newpts, out_att);
}

// Round 14
// 1133.402 us; speedup vs baseline: 1.0576x; 1.0576x over previous
//
#include <hip/hip_runtime.h>

#define NPTS 8192
#define NSAMP 1024
#define NBATCH 8
#define KNB 32

typedef float f32x2 __attribute__((ext_vector_type(2)));
typedef unsigned long long u64;

// Packed f32 ops — IEEE rn per half, identical results to scalar v_add/v_mul.
__device__ __forceinline__ f32x2 pk_add(f32x2 a, f32x2 b) {
  f32x2 d; asm("v_pk_add_f32 %0, %1, %2" : "=v"(d) : "v"(a), "v"(b)); return d;
}
__device__ __forceinline__ f32x2 pk_mul(f32x2 a, f32x2 b) {
  f32x2 d; asm("v_pk_mul_f32 %0, %1, %2" : "=v"(d) : "v"(a), "v"(b)); return d;
}

// Single-dep-chain DPP reduce rounds (old = own value, safe for min/max).
#define DPP_FMAX_ROUND(v, CTRL)                                                        \
  do {                                                                                 \
    int _b = __float_as_int(v);                                                        \
    int _p = __builtin_amdgcn_update_dpp(_b, _b, CTRL, 0xF, 0xF, false);               \
    (v) = fmaxf((v), __int_as_float(_p));                                              \
  } while (0)

#define DPP_FMIN_ROUND(v, CTRL)                                                        \
  do {                                                                                 \
    int _b = __float_as_int(v);                                                        \
    int _p = __builtin_amdgcn_update_dpp(_b, _b, CTRL, 0xF, 0xF, false);               \
    (v) = fminf((v), __int_as_float(_p));                                              \
  } while (0)

#define DPP_UMIN_ROUND(v, CTRL)                                                        \
  do {                                                                                 \
    unsigned _p = (unsigned)__builtin_amdgcn_update_dpp((int)(v), (int)(v), CTRL,      \
                                                        0xF, 0xF, false);              \
    if (_p < (v)) (v) = _p;                                                            \
  } while (0)

// u64 key min round — used for the 3 cross-wave rounds.
#define DPP_MIN_ROUND(k, CTRL)                                                         \
  do {                                                                                 \
    unsigned _lo = (unsigned)(k), _hi = (unsigned)((k) >> 32);                         \
    unsigned _plo = (unsigned)__builtin_amdgcn_update_dpp((int)_lo, (int)_lo, CTRL,    \
                                                          0xF, 0xF, false);            \
    unsigned _phi = (unsigned)__builtin_amdgcn_update_dpp((int)_hi, (int)_hi, CTRL,    \
                                                          0xF, 0xF, false);            \
    u64 _ok = (((u64)_phi) << 32) | _plo;                                              \
    if (_ok < (k)) (k) = _ok;                                                          \
  } while (0)

// Exact-match squared distance: ((dx*dx + dy*dy) + dz*dz), rn ops, no FMA.
__device__ __forceinline__ float sqdist_rn(float px, float py, float pz,
                                           float qx, float qy, float qz) {
  float dx = px - qx, dy = py - qy, dz = pz - qz;
  return __fadd_rn(__fadd_rn(__fmul_rn(dx, dx), __fmul_rn(dy, dy)), __fmul_rn(dz, dz));
}

// ---------------------------------------------------------------------------
// Kernel 1: farthest point sampling (R7 structure — measured 953 us, stable
// across 4 runs; 7 structural variants all measured worse).
// ---------------------------------------------------------------------------
__global__ __launch_bounds__(512) void fps_kernel(const float* __restrict__ xyz,
                                                  float* __restrict__ out_newxyz) {
  __shared__ __align__(16) char smem_raw[NPTS * 3 * 4];
  u64* sbuf = reinterpret_cast<u64*>(smem_raw);
  float* cds = reinterpret_cast<float*>(smem_raw);  // [n]={x,y,z}, stride 12B
  __shared__ u64 wkeys[2][8];

  const int b = blockIdx.x;
  const int tid = threadIdx.x;
  const int lane = tid & 63;
  const int wv = tid >> 6;
  const float* xb = xyz + (size_t)b * 3 * NPTS;

  // phase 0: sort keys (x >= 0 so u32 bit order == float order)
  for (int j = 0; j < 16; j++) {
    int n = tid + j * 512;
    float x = xb[n];
    sbuf[n] = (((u64)__float_as_uint(x)) << 32) | (u64)n;
  }
  __syncthreads();

  // bitonic sort ascending, 8192 u64 keys in LDS
  for (unsigned k = 2; k <= (unsigned)NPTS; k <<= 1) {
    for (unsigned jm = k >> 1; jm > 0; jm >>= 1) {
      for (int p = 0; p < 16; p++) {
        unsigned i = (unsigned)tid + (unsigned)p * 512u;
        unsigned ixj = i ^ jm;
        if (ixj > i) {
          u64 a = sbuf[i], c = sbuf[ixj];
          bool up = ((i & k) == 0);
          if ((a > c) == up) { sbuf[i] = c; sbuf[ixj] = a; }
        }
      }
      __syncthreads();
    }
  }

  // phase 1: thread t takes sorted slots [t*16, t*16+16)
  f32x2 X2[8], Y2[8], Z2[8], D2[8];
  unsigned idxp[8];
  float txmin = 1e30f, txmax = -1e30f;
#pragma unroll
  for (int j = 0; j < 8; j++) {
    u64 k0 = sbuf[tid * 16 + 2 * j];
    u64 k1 = sbuf[tid * 16 + 2 * j + 1];
    unsigned n0 = (unsigned)k0 & 8191u, n1 = (unsigned)k1 & 8191u;
    float x0 = __uint_as_float((unsigned)(k0 >> 32));
    float x1 = __uint_as_float((unsigned)(k1 >> 32));
    X2[j].x = x0; X2[j].y = x1;
    Y2[j].x = xb[NPTS + n0];     Y2[j].y = xb[NPTS + n1];
    Z2[j].x = xb[2 * NPTS + n0]; Z2[j].y = xb[2 * NPTS + n1];
    D2[j].x = 1e10f;             D2[j].y = 1e10f;
    idxp[j] = n0 | (n1 << 16);
    txmin = fminf(txmin, fminf(x0, x1));
    txmax = fmaxf(txmax, fmaxf(x0, x1));
  }
  DPP_FMIN_ROUND(txmin, 0x111); DPP_FMIN_ROUND(txmin, 0x112);
  DPP_FMIN_ROUND(txmin, 0x114); DPP_FMIN_ROUND(txmin, 0x118);
  DPP_FMIN_ROUND(txmin, 0x142); DPP_FMIN_ROUND(txmin, 0x143);
  DPP_FMAX_ROUND(txmax, 0x111); DPP_FMAX_ROUND(txmax, 0x112);
  DPP_FMAX_ROUND(txmax, 0x114); DPP_FMAX_ROUND(txmax, 0x118);
  DPP_FMAX_ROUND(txmax, 0x142); DPP_FMAX_ROUND(txmax, 0x143);
  const float xlo = __int_as_float(__builtin_amdgcn_readlane(__float_as_int(txmin), 63));
  const float xhi = __int_as_float(__builtin_amdgcn_readlane(__float_as_int(txmax), 63));
  __syncthreads();

  // phase 2: overlay cds (coords by ORIGINAL index)
#pragma unroll
  for (int j = 0; j < 8; j++) {
    unsigned n0 = idxp[j] & 0xFFFFu, n1 = idxp[j] >> 16;
    cds[n0 * 3 + 0] = X2[j].x; cds[n0 * 3 + 1] = Y2[j].x; cds[n0 * 3 + 2] = Z2[j].x;
    cds[n1 * 3 + 0] = X2[j].y; cds[n1 * 3 + 1] = Y2[j].y; cds[n1 * 3 + 2] = Z2[j].y;
  }
  __syncthreads();

  float sx = cds[0], sy = cds[1], sz = cds[2];
  unsigned c0i = 0, c1i = 0;
  float bv_cache = 1e10f;
  u64 key_cache = ~0ull;

  for (int t = 0; t < NSAMP; t++) {
    float gap = fmaxf(fmaxf(xlo - sx, sx - xhi), 0.0f);
    float lb = __fmul_rn(gap, gap);

    if (lb < bv_cache) {
      f32x2 nqx, nqy, nqz;
      nqx.x = -sx; nqx.y = -sx;
      nqy.x = -sy; nqy.y = -sy;
      nqz.x = -sz; nqz.y = -sz;
      float bvx = -1.0f, bvy = -1.0f;
#pragma unroll
      for (int j = 0; j < 8; j++) {
        f32x2 dx = pk_add(X2[j], nqx);
        f32x2 dy = pk_add(Y2[j], nqy);
        f32x2 dz = pk_add(Z2[j], nqz);
        f32x2 dd = pk_add(pk_add(pk_mul(dx, dx), pk_mul(dy, dy)), pk_mul(dz, dz));
        float m0 = fminf(D2[j].x, dd.x);
        float m1 = fminf(D2[j].y, dd.y);
        D2[j].x = m0;
        D2[j].y = m1;
        bvx = fmaxf(bvx, m0);
        bvy = fmaxf(bvy, m1);
      }
      float bv = fmaxf(bvx, bvy);

      DPP_FMAX_ROUND(bv, 0x111);
      DPP_FMAX_ROUND(bv, 0x112);
      DPP_FMAX_ROUND(bv, 0x114);
      DPP_FMAX_ROUND(bv, 0x118);
      DPP_FMAX_ROUND(bv, 0x142);
      DPP_FMAX_ROUND(bv, 0x143);
      float wval = __int_as_float(__builtin_amdgcn_readlane(__float_as_int(bv), 63));

      unsigned cand = 0xFFFFFFFFu;
#pragma unroll
      for (int j = 0; j < 8; j++) {
        unsigned n0 = idxp[j] & 0xFFFFu, n1 = idxp[j] >> 16;
        if (D2[j].y == wval && n1 < cand) cand = n1;
        if (D2[j].x == wval && n0 < cand) cand = n0;
      }
      DPP_UMIN_ROUND(cand, 0x111);
      DPP_UMIN_ROUND(cand, 0x112);
      DPP_UMIN_ROUND(cand, 0x114);
      DPP_UMIN_ROUND(cand, 0x118);
      DPP_UMIN_ROUND(cand, 0x142);
      DPP_UMIN_ROUND(cand, 0x143);

      key_cache = (((u64)(~__float_as_uint(wval))) << 32) | (u64)cand;
      bv_cache = wval;
    }

    const int par = t & 1;
    if (lane == 63) wkeys[par][wv] = key_cache;
    __syncthreads();
    u64 k8 = wkeys[par][lane & 7];
    DPP_MIN_ROUND(k8, 0xB1);   // quad_perm ^1
    DPP_MIN_ROUND(k8, 0x4E);   // quad_perm ^2
    DPP_MIN_ROUND(k8, 0x141);  // row_half_mirror
    unsigned wid = (unsigned)__builtin_amdgcn_readfirstlane((int)(unsigned)k8);

    if (t + 1 == tid) c0i = wid;
    if (t + 1 == tid + 512) c1i = wid;

    sx = cds[wid * 3 + 0];
    sy = cds[wid * 3 + 1];
    sz = cds[wid * 3 + 2];
  }

  {
    float ax = cds[c0i * 3 + 0], ay = cds[c0i * 3 + 1], az = cds[c0i * 3 + 2];
    float bx = cds[c1i * 3 + 0], by = cds[c1i * 3 + 1], bz = cds[c1i * 3 + 2];
    out_newxyz[(b * 3 + 0) * NSAMP + tid] = ax;
    out_newxyz[(b * 3 + 1) * NSAMP + tid] = ay;
    out_newxyz[(b * 3 + 2) * NSAMP + tid] = az;
    out_newxyz[(b * 3 + 0) * NSAMP + 512 + tid] = bx;
    out_newxyz[(b * 3 + 1) * NSAMP + 512 + tid] = by;
    out_newxyz[(b * 3 + 2) * NSAMP + 512 + tid] = bz;
  }
}

// ---------------------------------------------------------------------------
// Kernel 2 (fused consumer, R12 configuration — measured best at 180 us):
// per sample — ball query (wave 0, indices to LDS) + attention mean +
// gather + 3-layer MLP + max-pool. One 256-thread block per (b,s); ~27 KB
// LDS keeps ~5 blocks/CU for gather L2 locality. Each thread owns 2 output
// rows; w1/w2 weight rows are 256 B-strided -> aligned float4 loads (FMA
// order unchanged, bitwise-same output).
// ---------------------------------------------------------------------------
__global__ __launch_bounds__(256) void sample_kernel(
    const float* __restrict__ xyz, const float* __restrict__ pts,
    const float* __restrict__ att, const float* __restrict__ newxyz,
    const float* __restrict__ w0, const float* __restrict__ b0,
    const float* __restrict__ w1, const float* __restrict__ b1,
    const float* __restrict__ w2, const float* __restrict__ b2,
    float* __restrict__ out_np, float* __restrict__ att_out) {
  const int g = blockIdx.x;
  const int b = g >> 10;
  const int s = g & 1023;
  const int t = threadIdx.x;

  __shared__ __align__(16) float feat[67 * 32];
  __shared__ __align__(16) float h0s[64 * 36];
  __shared__ __align__(16) float h1s[64 * 36];
  __shared__ int sidx[KNB];
  __shared__ float qs[3];

  const float* xb = xyz + (size_t)b * 3 * NPTS;

  // ---- wave 0: ball query (first-K in index order) + attention mean ----
  if (t < 64) {
    const int lane = t;
    float qx = newxyz[(b * 3 + 0) * NSAMP + s];
    float qy = newxyz[(b * 3 + 1) * NSAMP + s];
    float qz = newxyz[(b * 3 + 2) * NSAMP + s];
    if (lane == 0) { qs[0] = qx; qs[1] = qy; qs[2] = qz; }

    int have = 0;
    int firstn = 0;
    for (int c = 0; c < NPTS / 64; c++) {
      int n = c * 64 + lane;
      float dd = sqdist_rn(xb[n], xb[NPTS + n], xb[2 * NPTS + n], qx, qy, qz);
      bool inb = (dd <= 0.04f);
      unsigned long long m = __ballot(inb);
      if (have == 0 && m != 0ull) firstn = c * 64 + __builtin_ctzll(m);
      int pre = __popcll(m & ((1ull << lane) - 1ull));
      if (inb && (have + pre) < KNB) sidx[have + pre] = n;
      have += __popcll(m);
      if (have >= KNB) break;
    }
    if (have > KNB) have = KNB;
    if (lane < KNB && lane >= have) sidx[lane] = firstn;  // pad with first hit

    float av = 0.0f;
    if (lane < KNB) av = att[(size_t)b * NPTS + sidx[lane]];
#pragma unroll
    for (int m = 1; m < 64; m <<= 1) av += __shfl_xor(av, m, 64);
    if (lane == 0) att_out[g] = av * 0.03125f;  // mean over K=32 (exact /32)
  }
  __syncthreads();

  // ---- gather: rows 0..2 = g_norm (xyz - query), rows 3..66 = features ----
  {
    int k = t & 31, rg = t >> 5;
    int n = sidx[k];
    const float* pb = pts + (size_t)b * 64 * NPTS;
    for (int r = rg; r < 67; r += 8) {
      float v;
      if (r < 3)
        v = xyz[((size_t)b * 3 + r) * NPTS + n] - qs[r];
      else
        v = pb[(size_t)(r - 3) * NPTS + n];
      feat[r * 32 + k] = v;
    }
  }
  __syncthreads();

  const int kq = t & 7;   // k block = 4*kq .. +4
  const int og = t >> 3;  // o = 2*og, 2*og+1

  // ---- layer 0: 67 -> 64 (w0 rows are 268B-strided: scalar loads) ----
  {
    float a0[8];
    float bu = b0[2 * og], bw = b0[2 * og + 1];
    a0[0] = a0[1] = a0[2] = a0[3] = bu;
    a0[4] = a0[5] = a0[6] = a0[7] = bw;
    const float* wr0 = w0 + (2 * og) * 67;
    const float* wr1 = wr0 + 67;
    for (int c = 0; c < 67; c++) {
      float4 f = *(const float4*)&feat[c * 32 + kq * 4];
      float u = wr0[c], v = wr1[c];
      a0[0] = fmaf(u, f.x, a0[0]); a0[1] = fmaf(u, f.y, a0[1]);
      a0[2] = fmaf(u, f.z, a0[2]); a0[3] = fmaf(u, f.w, a0[3]);
      a0[4] = fmaf(v, f.x, a0[4]); a0[5] = fmaf(v, f.y, a0[5]);
      a0[6] = fmaf(v, f.z, a0[6]); a0[7] = fmaf(v, f.w, a0[7]);
    }
    float4 r0, r1;
    r0.x = fmaxf(a0[0], 0.f); r0.y = fmaxf(a0[1], 0.f);
    r0.z = fmaxf(a0[2], 0.f); r0.w = fmaxf(a0[3], 0.f);
    r1.x = fmaxf(a0[4], 0.f); r1.y = fmaxf(a0[5], 0.f);
    r1.z = fmaxf(a0[6], 0.f); r1.w = fmaxf(a0[7], 0.f);
    *(float4*)&h0s[(2 * og) * 36 + kq * 4] = r0;
    *(float4*)&h0s[(2 * og + 1) * 36 + kq * 4] = r1;
  }
  __syncthreads();

  // ---- layer 1: 64 -> 64 (float4 weight loads; FMA order unchanged) ----
  {
    float a1[8];
    float bu = b1[2 * og], bw = b1[2 * og + 1];
    a1[0] = a1[1] = a1[2] = a1[3] = bu;
    a1[4] = a1[5] = a1[6] = a1[7] = bw;
    const float4* wv0 = (const float4*)(w1 + (2 * og) * 64);
    const float4* wv1 = (const float4*)(w1 + (2 * og + 1) * 64);
    for (int c4 = 0; c4 < 16; c4++) {
      float4 u4 = wv0[c4], v4 = wv1[c4];
#pragma unroll
      for (int i = 0; i < 4; i++) {
        int c = c4 * 4 + i;
        float u = (i == 0) ? u4.x : (i == 1) ? u4.y : (i == 2) ? u4.z : u4.w;
        float v = (i == 0) ? v4.x : (i == 1) ? v4.y : (i == 2) ? v4.z : v4.w;
        float4 f = *(const float4*)&h0s[c * 36 + kq * 4];
        a1[0] = fmaf(u, f.x, a1[0]); a1[1] = fmaf(u, f.y, a1[1]);
        a1[2] = fmaf(u, f.z, a1[2]); a1[3] = fmaf(u, f.w, a1[3]);
        a1[4] = fmaf(v, f.x, a1[4]); a1[5] = fmaf(v, f.y, a1[5]);
        a1[6] = fmaf(v, f.z, a1[6]); a1[7] = fmaf(v, f.w, a1[7]);
      }
    }
    float4 r0, r1;
    r0.x = fmaxf(a1[0], 0.f); r0.y = fmaxf(a1[1], 0.f);
    r0.z = fmaxf(a1[2], 0.f); r0.w = fmaxf(a1[3], 0.f);
    r1.x = fmaxf(a1[4], 0.f); r1.y = fmaxf(a1[5], 0.f);
    r1.z = fmaxf(a1[6], 0.f); r1.w = fmaxf(a1[7], 0.f);
    *(float4*)&h1s[(2 * og) * 36 + kq * 4] = r0;
    *(float4*)&h1s[(2 * og + 1) * 36 + kq * 4] = r1;
  }
  __syncthreads();

  // ---- layer 2: 64 -> 128 (float4 weight loads), then max over k ----
  {
    const int kq2 = t & 3;   // k block = 8*kq2 .. +8
    const int og2 = t >> 2;  // o = 2*og2, 2*og2+1
    float a2[16];
    float bu = b2[2 * og2], bw = b2[2 * og2 + 1];
#pragma unroll
    for (int i = 0; i < 8; i++) { a2[i] = bu; a2[8 + i] = bw; }
    const float4* wv0 = (const float4*)(w2 + (2 * og2) * 64);
    const float4* wv1 = (const float4*)(w2 + (2 * og2 + 1) * 64);
    for (int c4 = 0; c4 < 16; c4++) {
      float4 u4 = wv0[c4], v4 = wv1[c4];
#pragma unroll
      for (int i = 0; i < 4; i++) {
        int c = c4 * 4 + i;
        float u = (i == 0) ? u4.x : (i == 1) ? u4.y : (i == 2) ? u4.z : u4.w;
        float v = (i == 0) ? v4.x : (i == 1) ? v4.y : (i == 2) ? v4.z : v4.w;
        float4 fA = *(const float4*)&h1s[c * 36 + kq2 * 8];
        float4 fB = *(const float4*)&h1s[c * 36 + kq2 * 8 + 4];
        a2[0] = fmaf(u, fA.x, a2[0]);  a2[1] = fmaf(u, fA.y, a2[1]);
        a2[2] = fmaf(u, fA.z, a2[2]);  a2[3] = fmaf(u, fA.w, a2[3]);
        a2[4] = fmaf(u, fB.x, a2[4]);  a2[5] = fmaf(u, fB.y, a2[5]);
        a2[6] = fmaf(u, fB.z, a2[6]);  a2[7] = fmaf(u, fB.w, a2[7]);
        a2[8] = fmaf(v, fA.x, a2[8]);  a2[9] = fmaf(v, fA.y, a2[9]);
        a2[10] = fmaf(v, fA.z, a2[10]); a2[11] = fmaf(v, fA.w, a2[11]);
        a2[12] = fmaf(v, fB.x, a2[12]); a2[13] = fmaf(v, fB.y, a2[13]);
        a2[14] = fmaf(v, fB.z, a2[14]); a2[15] = fmaf(v, fB.w, a2[15]);
      }
    }
    // relu then max over k == max then relu (relu is monotone)
    float m0 = a2[0], m1 = a2[8];
#pragma unroll
    for (int i = 1; i < 8; i++) { m0 = fmaxf(m0, a2[i]); m1 = fmaxf(m1, a2[8 + i]); }
    m0 = fmaxf(m0, 0.f);
    m1 = fmaxf(m1, 0.f);
    // reduce over the 4 lanes sharing og2 (kq2 = 0..3, adjacent lanes)
    m0 = fmaxf(m0, __shfl_xor(m0, 1, 64));
    m0 = fmaxf(m0, __shfl_xor(m0, 2, 64));
    m1 = fmaxf(m1, __shfl_xor(m1, 1, 64));
    m1 = fmaxf(m1, __shfl_xor(m1, 2, 64));
    if (kq2 == 0) {
      out_np[((size_t)b * 128 + 2 * og2) * NSAMP + s] = m0;
      out_np[((size_t)b * 128 + 2 * og2 + 1) * NSAMP + s] = m1;
    }
  }
}

extern "C" void kernel_launch(void* const* d_in, const int* in_sizes, int n_in,
                              void* d_out, int out_size, void* d_ws, size_t ws_size,
                              hipStream_t stream) {
  (void)in_sizes; (void)n_in; (void)out_size; (void)d_ws; (void)ws_size;
  const float* xyz = (const float*)d_in[0];
  const float* pts = (const float*)d_in[1];
  const float* att = (const float*)d_in[2];
  const float* w0 = (const float*)d_in[3];
  const float* b0 = (const float*)d_in[4];
  const float* w1 = (const float*)d_in[5];
  const float* b1 = (const float*)d_in[6];
  const float* w2 = (const float*)d_in[7];
  const float* b2 = (const float*)d_in[8];

  float* out = (float*)d_out;
  float* out_newxyz = out;                                           // (B,3,S)
  float* out_newpts = out + NBATCH * 3 * NSAMP;                      // (B,128,S)
  float* out_att = out + NBATCH * 3 * NSAMP + NBATCH * 128 * NSAMP;  // (B,1,S)

  fps_kernel<<<NBATCH, 512, 0, stream>>>(xyz, out_newxyz);
  sample_kernel<<<NBATCH * NSAMP, 256, 0, stream>>>(
      xyz, pts, att, out_newxyz, w0, b0, w1, b1, w2, b2, out_newpts, out_att);
}